// Round 1
// baseline (1051.923 us; speedup 1.0000x reference)
//
#include <hip/hip_runtime.h>
#include <hip/hip_bf16.h>

// Problem constants (from reference)
#define GENES 12132
#define NROW  16384
#define GCOL  64

// GEMM tiling
#define BM 256        // rows per block (= threads, lane = row)
#define BK 32         // k per staged chunk
#define KSPLIT 8
#define NCHUNK ((GENES + BK - 1) / BK)          // 380
#define CPB    ((NCHUNK + KSPLIT - 1) / KSPLIT) // 48

// ---------------- prep: W' = gcn_weight / node_scales[row]; zero xw, res ----
__global__ __launch_bounds__(256) void prep_kernel(
    const float* __restrict__ gw, const float* __restrict__ ns,
    float* __restrict__ Wp, float* __restrict__ xw, float* __restrict__ res) {
  int i = blockIdx.x * blockDim.x + threadIdx.x;
  int stride = gridDim.x * blockDim.x;
  for (int j = i; j < GENES * GCOL; j += stride) {
    Wp[j] = gw[j] / ns[j >> 6];           // j = m*64 + c -> scale by ns[m]
  }
  for (int j = i; j < NROW * GCOL; j += stride) xw[j] = 0.f;
  if (i == 0) *res = 0.f;
}

// ---------------- GEMM: xw[N,64] += x[N,K] @ Wp[K,64] -----------------------
__global__ __launch_bounds__(256, 2) void gemm_kernel(
    const float* __restrict__ x, const float* __restrict__ Wp,
    float* __restrict__ xw) {
  __shared__ float aT[BK][BM + 1];   // transposed x tile, stride 257 (bank-friendly)

  const int t  = threadIdx.x;
  const int rb = blockIdx.x & 63;    // 64 row-blocks
  const int ks = blockIdx.x >> 6;    // 8 k-splits
  const int r0 = rb * BM;
  const int c0 = ks * CPB;
  const int c1 = (c0 + CPB < NCHUNK) ? (c0 + CPB) : NCHUNK;

  float acc[GCOL];
#pragma unroll
  for (int c = 0; c < GCOL; ++c) acc[c] = 0.f;

  for (int ch = c0; ch < c1; ++ch) {
    const int k0 = ch * BK;
    __syncthreads();   // protect aT from previous iteration's readers
    // stage 256 rows x 32 k, transposed. Each thread: 8 float4 loads.
#pragma unroll
    for (int i = 0; i < 8; ++i) {
      int li  = t + i * 256;          // 0..2047
      int row = li >> 3;              // 0..255
      int k4  = (li & 7) * 4;         // 0..28
      int gk  = k0 + k4;
      float4 v;
      if (gk + 3 < GENES) {
        v = *reinterpret_cast<const float4*>(&x[(size_t)(r0 + row) * GENES + gk]);
      } else {
        float tmp[4] = {0.f, 0.f, 0.f, 0.f};
#pragma unroll
        for (int j = 0; j < 4; ++j)
          if (gk + j < GENES) tmp[j] = x[(size_t)(r0 + row) * GENES + gk + j];
        v = make_float4(tmp[0], tmp[1], tmp[2], tmp[3]);
      }
      aT[k4 + 0][row] = v.x;
      aT[k4 + 1][row] = v.y;
      aT[k4 + 2][row] = v.z;
      aT[k4 + 3][row] = v.w;
    }
    __syncthreads();

    const int krem = GENES - k0;
    const int kmax = (krem < BK) ? krem : BK;
    if (kmax == BK) {
      for (int kk = 0; kk < BK; ++kk) {
        float a = aT[kk][t];
        const float* __restrict__ wrow = Wp + (size_t)(k0 + kk) * GCOL;  // wave-uniform -> s_load
#pragma unroll
        for (int c = 0; c < GCOL; ++c) acc[c] = fmaf(a, wrow[c], acc[c]);
      }
    } else {
      for (int kk = 0; kk < kmax; ++kk) {
        float a = aT[kk][t];
        const float* __restrict__ wrow = Wp + (size_t)(k0 + kk) * GCOL;
#pragma unroll
        for (int c = 0; c < GCOL; ++c) acc[c] = fmaf(a, wrow[c], acc[c]);
      }
    }
  }

  float* xrow = xw + (size_t)(r0 + t) * GCOL;
#pragma unroll
  for (int c = 0; c < GCOL; ++c) atomicAdd(&xrow[c], acc[c]);
}

// ---------------- selected init: sel[i] = xw[i, g_i] + bias[g_i] ------------
__global__ __launch_bounds__(256) void sel_init_kernel(
    const float* __restrict__ xw, const int* __restrict__ gid,
    const float* __restrict__ bias, float* __restrict__ sel) {
  int i = blockIdx.x * 256 + threadIdx.x;
  int g = gid[i];
  sel[i] = xw[(size_t)i * GCOL + g] + bias[g];
}

// ---------------- edge scatter: sel[dst] += xw[src, g_dst] ------------------
__global__ __launch_bounds__(256) void edge_kernel(
    const int* __restrict__ ei, const int* __restrict__ gid,
    const float* __restrict__ xw, float* __restrict__ sel, int E) {
  int i = blockIdx.x * blockDim.x + threadIdx.x;
  int stride = gridDim.x * blockDim.x;
  for (int e = i; e < E; e += stride) {
    int s = ei[e];
    int d = ei[E + e];
    int g = gid[d];
    atomicAdd(&sel[d], xw[(size_t)s * GCOL + g]);
  }
}

// ---------------- h[k] = w1[k,:] . sel; normalize; res += w2[k]*hn ----------
__global__ __launch_bounds__(256) void hreduce_kernel(
    const float* __restrict__ w1, const float* __restrict__ sel,
    const float* __restrict__ b1, const float* __restrict__ fm,
    const float* __restrict__ fs, const float* __restrict__ w2,
    float* __restrict__ res) {
  int k = blockIdx.x;
  int t = threadIdx.x;
  const float4* wr = reinterpret_cast<const float4*>(w1 + (size_t)k * NROW);
  const float4* sv = reinterpret_cast<const float4*>(sel);
  float sum = 0.f;
  for (int i = t; i < NROW / 4; i += 256) {
    float4 a = wr[i];
    float4 b = sv[i];
    sum += a.x * b.x + a.y * b.y + a.z * b.z + a.w * b.w;
  }
#pragma unroll
  for (int off = 32; off > 0; off >>= 1) sum += __shfl_down(sum, off, 64);
  __shared__ float wsum[4];
  if ((t & 63) == 0) wsum[t >> 6] = sum;
  __syncthreads();
  if (t == 0) {
    float h  = wsum[0] + wsum[1] + wsum[2] + wsum[3] + b1[k];
    float hn = (h - fm[k]) / fs[k];
    atomicAdd(res, w2[k] * hn);
  }
}

// ---------------- finalize: out = sigmoid(res + b2) -------------------------
__global__ void finalize_kernel(const float* __restrict__ res,
                                const float* __restrict__ b2,
                                float* __restrict__ out) {
  float z = *res + b2[0];
  out[0] = 1.f / (1.f + expf(-z));
}

extern "C" void kernel_launch(void* const* d_in, const int* in_sizes, int n_in,
                              void* d_out, int out_size, void* d_ws, size_t ws_size,
                              hipStream_t stream) {
  const float* x    = (const float*)d_in[0];
  const int*   ei   = (const int*)d_in[1];
  const int*   gid  = (const int*)d_in[2];
  const float* ns   = (const float*)d_in[3];
  const float* gw   = (const float*)d_in[4];
  const float* gb   = (const float*)d_in[5];
  const float* w1   = (const float*)d_in[6];
  const float* b1   = (const float*)d_in[7];
  const float* fm   = (const float*)d_in[8];
  const float* fs   = (const float*)d_in[9];
  const float* w2   = (const float*)d_in[10];
  const float* b2   = (const float*)d_in[11];
  float* out = (float*)d_out;

  const int E = in_sizes[1] / 2;

  float* ws  = (float*)d_ws;
  float* xw  = ws;                                  // N*G      = 1,048,576
  float* Wp  = ws + (size_t)NROW * GCOL;            // GENES*G  =   776,448
  float* sel = Wp + (size_t)GENES * GCOL;           // N        =    16,384
  float* res = sel + NROW;                          // 1

  hipLaunchKernelGGL(prep_kernel, dim3(1024), dim3(256), 0, stream,
                     gw, ns, Wp, xw, res);
  hipLaunchKernelGGL(gemm_kernel, dim3(64 * KSPLIT), dim3(256), 0, stream,
                     x, Wp, xw);
  hipLaunchKernelGGL(sel_init_kernel, dim3(NROW / 256), dim3(256), 0, stream,
                     xw, gid, gb, sel);
  hipLaunchKernelGGL(edge_kernel, dim3(1024), dim3(256), 0, stream,
                     ei, gid, xw, sel, E);
  hipLaunchKernelGGL(hreduce_kernel, dim3(GCOL), dim3(256), 0, stream,
                     w1, sel, b1, fm, fs, w2, res);
  hipLaunchKernelGGL(finalize_kernel, dim3(1), dim3(1), 0, stream,
                     res, b2, out);
}

// Round 2
// 418.319 us; speedup vs baseline: 2.5146x; 2.5146x over previous
//
#include <hip/hip_runtime.h>
#include <hip/hip_bf16.h>

typedef unsigned short u16;
typedef unsigned int   u32;
typedef __attribute__((ext_vector_type(8))) short bf16x8;
typedef __attribute__((ext_vector_type(4))) float f32x4;

#define GENES 12132
#define KPAD  12160        // 190 * 64, zero-padded W tail
#define NROW  16384
#define GCOL  64
#define BM    128
#define BK    64
#define CHUNKS 190
#define KSPLIT 8
#define CPB   24           // ceil(190/8)

// split fp32 into bf16 hi (truncation) + bf16 lo (residual), x ~= hi + lo, err <= 2^-16 |x|
__device__ __forceinline__ void split2(float x, u16& h, u16& l) {
  u32 u = __float_as_uint(x);
  h = (u16)(u >> 16);
  float hf = __uint_as_float(u & 0xFFFF0000u);
  float lf = x - hf;                       // exact (Sterbenz)
  l = (u16)(__float_as_uint(lf) >> 16);
}

// ---------------- prep: W'[k][c] = gw[k][c]/ns[k] -> transposed bf16 hi/lo planes
// Wth/Wtl layout: [c][k] with k padded to KPAD (zeros beyond GENES)
__global__ __launch_bounds__(256) void prep_w(
    const float* __restrict__ gw, const float* __restrict__ ns,
    u16* __restrict__ Wth, u16* __restrict__ Wtl) {
  __shared__ u16 th[64 * 72];
  __shared__ u16 tl[64 * 72];
  const int t  = threadIdx.x;
  const int k0 = blockIdx.x * 64;
#pragma unroll
  for (int i = 0; i < 16; ++i) {
    int idx = i * 256 + t;          // 0..4095
    int k = idx >> 6, c = idx & 63;
    int gk = k0 + k;
    float wv = 0.f;
    if (gk < GENES) wv = gw[(size_t)gk * GCOL + c] / ns[gk];
    u16 h, lo;
    split2(wv, h, lo);
    th[c * 72 + k] = h;
    tl[c * 72 + k] = lo;
  }
  __syncthreads();
  const int c  = t >> 2;
  const int kk = (t & 3) * 16;
  uint4 a0 = *(const uint4*)(th + c * 72 + kk);
  uint4 a1 = *(const uint4*)(th + c * 72 + kk + 8);
  uint4 b0 = *(const uint4*)(tl + c * 72 + kk);
  uint4 b1 = *(const uint4*)(tl + c * 72 + kk + 8);
  *(uint4*)(Wth + (size_t)c * KPAD + k0 + kk)     = a0;
  *(uint4*)(Wth + (size_t)c * KPAD + k0 + kk + 8) = a1;
  *(uint4*)(Wtl + (size_t)c * KPAD + k0 + kk)     = b0;
  *(uint4*)(Wtl + (size_t)c * KPAD + k0 + kk + 8) = b1;
}

// ---------------- GEMM: xw[N,64] += x[N,K] @ W'[K,64] via split-bf16 MFMA ----
__global__ __launch_bounds__(256, 3) void gemm_kernel(
    const float* __restrict__ x, const u16* __restrict__ Wth,
    const u16* __restrict__ Wtl, float* __restrict__ xw) {
  // XOR-swizzled LDS: byte(row,k) = row*128 + (((k>>3) ^ (row&7))<<4) + (k&7)*2
  __shared__ u16 Ah[BM * 64];
  __shared__ u16 Al[BM * 64];
  __shared__ u16 Bh[64 * 64];
  __shared__ u16 Bl[64 * 64];

  const int t  = threadIdx.x;
  const int rb = blockIdx.x & 127;
  const int ks = blockIdx.x >> 7;
  const int r0 = rb * BM;
  const int c0 = ks * CPB;
  const int c1 = (c0 + CPB < CHUNKS) ? (c0 + CPB) : CHUNKS;

  const int w  = t >> 6;
  const int l  = t & 63;
  const int lr = l & 15;     // fragment row/col
  const int kg = l >> 4;     // k-group

  // LDS fragment offsets (ushort indices), chunk-invariant
  int aoff[2][2], boff[4][2];
#pragma unroll
  for (int m = 0; m < 2; ++m) {
    int row = w * 32 + m * 16 + lr;
#pragma unroll
    for (int s = 0; s < 2; ++s)
      aoff[m][s] = row * 64 + (((s * 4 + kg) ^ (row & 7)) << 3);
  }
#pragma unroll
  for (int n = 0; n < 4; ++n) {
    int c = n * 16 + lr;
#pragma unroll
    for (int s = 0; s < 2; ++s)
      boff[n][s] = c * 64 + (((s * 4 + kg) ^ (c & 7)) << 3);
  }

  f32x4 acc[2][4];
#pragma unroll
  for (int m = 0; m < 2; ++m)
#pragma unroll
    for (int n = 0; n < 4; ++n)
      acc[m][n] = (f32x4){0.f, 0.f, 0.f, 0.f};

  const int arow = t >> 4;          // 0..15
  const int ak4  = (t & 15) * 4;    // 0..60
  const int bc   = t >> 2;          // 0..63
  const int bkk  = (t & 3) * 16;    // 0,16,32,48

  for (int ch = c0; ch < c1; ++ch) {
    const int k0 = ch * BK;
    __syncthreads();
    // ---- stage B: Wt hi/lo tiles (bf16, already transposed) ----
    {
      const uint4* gh = (const uint4*)(Wth + (size_t)bc * KPAD + k0 + bkk);
      const uint4* gl = (const uint4*)(Wtl + (size_t)bc * KPAD + k0 + bkk);
      uint4 vh0 = gh[0], vh1 = gh[1];
      uint4 vl0 = gl[0], vl1 = gl[1];
      int g0 = bkk >> 3;
      int i0 = bc * 64 + ((g0 ^ (bc & 7)) << 3);
      int i1 = bc * 64 + (((g0 + 1) ^ (bc & 7)) << 3);
      *(uint4*)(Bh + i0) = vh0;
      *(uint4*)(Bh + i1) = vh1;
      *(uint4*)(Bl + i0) = vl0;
      *(uint4*)(Bl + i1) = vl1;
    }
    // ---- stage A: x fp32 tile -> bf16 hi/lo ----
    const bool full = (k0 + BK <= GENES);
#pragma unroll
    for (int i = 0; i < 8; ++i) {
      int row = arow + i * 16;
      const float* rp = x + (size_t)(r0 + row) * GENES + k0 + ak4;
      float4 v;
      if (full) {
        v = *(const float4*)rp;
      } else {
        int kb = k0 + ak4;
        v.x = (kb + 0 < GENES) ? rp[0] : 0.f;
        v.y = (kb + 1 < GENES) ? rp[1] : 0.f;
        v.z = (kb + 2 < GENES) ? rp[2] : 0.f;
        v.w = (kb + 3 < GENES) ? rp[3] : 0.f;
      }
      u16 h0, h1, h2, h3, l0, l1, l2, l3;
      split2(v.x, h0, l0); split2(v.y, h1, l1);
      split2(v.z, h2, l2); split2(v.w, h3, l3);
      uint2 hp, lp;
      hp.x = (u32)h0 | ((u32)h1 << 16);
      hp.y = (u32)h2 | ((u32)h3 << 16);
      lp.x = (u32)l0 | ((u32)l1 << 16);
      lp.y = (u32)l2 | ((u32)l3 << 16);
      int idx = row * 64 + (((ak4 >> 3) ^ (row & 7)) << 3) + (ak4 & 7);
      *(uint2*)(Ah + idx) = hp;
      *(uint2*)(Al + idx) = lp;
    }
    __syncthreads();
    // ---- compute: acc += Ah*Bh + Ah*Bl + Al*Bh ----
#pragma unroll
    for (int s = 0; s < 2; ++s) {
      bf16x8 ah0 = *(const bf16x8*)(Ah + aoff[0][s]);
      bf16x8 ah1 = *(const bf16x8*)(Ah + aoff[1][s]);
      bf16x8 al0 = *(const bf16x8*)(Al + aoff[0][s]);
      bf16x8 al1 = *(const bf16x8*)(Al + aoff[1][s]);
#pragma unroll
      for (int n = 0; n < 4; ++n) {
        bf16x8 bhn = *(const bf16x8*)(Bh + boff[n][s]);
        bf16x8 bln = *(const bf16x8*)(Bl + boff[n][s]);
        acc[0][n] = __builtin_amdgcn_mfma_f32_16x16x32_bf16(ah0, bhn, acc[0][n], 0, 0, 0);
        acc[1][n] = __builtin_amdgcn_mfma_f32_16x16x32_bf16(ah1, bhn, acc[1][n], 0, 0, 0);
        acc[0][n] = __builtin_amdgcn_mfma_f32_16x16x32_bf16(al0, bhn, acc[0][n], 0, 0, 0);
        acc[1][n] = __builtin_amdgcn_mfma_f32_16x16x32_bf16(al1, bhn, acc[1][n], 0, 0, 0);
        acc[0][n] = __builtin_amdgcn_mfma_f32_16x16x32_bf16(ah0, bln, acc[0][n], 0, 0, 0);
        acc[1][n] = __builtin_amdgcn_mfma_f32_16x16x32_bf16(ah1, bln, acc[1][n], 0, 0, 0);
      }
    }
  }

  // ---- epilogue: merge k-splits (C/D layout: col=lane&15, row=(lane>>4)*4+reg)
#pragma unroll
  for (int m = 0; m < 2; ++m) {
#pragma unroll
    for (int n = 0; n < 4; ++n) {
      int row = r0 + w * 32 + m * 16 + kg * 4;
      int col = n * 16 + lr;
      float* p = xw + (size_t)row * GCOL + col;
      atomicAdd(p,            acc[m][n][0]);
      atomicAdd(p + GCOL,     acc[m][n][1]);
      atomicAdd(p + 2 * GCOL, acc[m][n][2]);
      atomicAdd(p + 3 * GCOL, acc[m][n][3]);
    }
  }
}

// ---------------- selected init: sel[i] = xw[i, g_i] + bias[g_i]; res = 0 ----
__global__ __launch_bounds__(256) void sel_init_kernel(
    const float* __restrict__ xw, const int* __restrict__ gid,
    const float* __restrict__ bias, float* __restrict__ sel,
    float* __restrict__ res) {
  int i = blockIdx.x * 256 + threadIdx.x;
  int g = gid[i];
  sel[i] = xw[(size_t)i * GCOL + g] + bias[g];
  if (i == 0) *res = 0.f;
}

// ---------------- edge scatter: sel[dst] += xw[src, g_dst] ------------------
__global__ __launch_bounds__(256) void edge_kernel(
    const int* __restrict__ ei, const int* __restrict__ gid,
    const float* __restrict__ xw, float* __restrict__ sel, int E) {
  int i = blockIdx.x * blockDim.x + threadIdx.x;
  int stride = gridDim.x * blockDim.x;
  for (int e = i; e < E; e += stride) {
    int s = ei[e];
    int d = ei[E + e];
    int g = gid[d];
    atomicAdd(&sel[d], xw[(size_t)s * GCOL + g]);
  }
}

// ---------------- h[k] = w1[k,:] . sel; normalize; res += w2[k]*hn ----------
__global__ __launch_bounds__(256) void hreduce_kernel(
    const float* __restrict__ w1, const float* __restrict__ sel,
    const float* __restrict__ b1, const float* __restrict__ fm,
    const float* __restrict__ fs, const float* __restrict__ w2,
    float* __restrict__ res) {
  int k = blockIdx.x;
  int t = threadIdx.x;
  const float4* wr = reinterpret_cast<const float4*>(w1 + (size_t)k * NROW);
  const float4* sv = reinterpret_cast<const float4*>(sel);
  float sum = 0.f;
  for (int i = t; i < NROW / 4; i += 256) {
    float4 a = wr[i];
    float4 b = sv[i];
    sum += a.x * b.x + a.y * b.y + a.z * b.z + a.w * b.w;
  }
#pragma unroll
  for (int off = 32; off > 0; off >>= 1) sum += __shfl_down(sum, off, 64);
  __shared__ float wsum[4];
  if ((t & 63) == 0) wsum[t >> 6] = sum;
  __syncthreads();
  if (t == 0) {
    float h  = wsum[0] + wsum[1] + wsum[2] + wsum[3] + b1[k];
    float hn = (h - fm[k]) / fs[k];
    atomicAdd(res, w2[k] * hn);
  }
}

// ---------------- finalize: out = sigmoid(res + b2) -------------------------
__global__ void finalize_kernel(const float* __restrict__ res,
                                const float* __restrict__ b2,
                                float* __restrict__ out) {
  float z = *res + b2[0];
  out[0] = 1.f / (1.f + expf(-z));
}

extern "C" void kernel_launch(void* const* d_in, const int* in_sizes, int n_in,
                              void* d_out, int out_size, void* d_ws, size_t ws_size,
                              hipStream_t stream) {
  const float* x    = (const float*)d_in[0];
  const int*   ei   = (const int*)d_in[1];
  const int*   gid  = (const int*)d_in[2];
  const float* ns   = (const float*)d_in[3];
  const float* gw   = (const float*)d_in[4];
  const float* gb   = (const float*)d_in[5];
  const float* w1   = (const float*)d_in[6];
  const float* b1   = (const float*)d_in[7];
  const float* fm   = (const float*)d_in[8];
  const float* fs   = (const float*)d_in[9];
  const float* w2   = (const float*)d_in[10];
  const float* b2   = (const float*)d_in[11];
  float* out = (float*)d_out;

  const int E = in_sizes[1] / 2;

  float* ws  = (float*)d_ws;
  float* xw  = ws;                                   // 1,048,576 f32
  float* sel = ws + (size_t)NROW * GCOL;             // 16,384 f32 (16B-aligned)
  float* res = sel + NROW;                           // 1 f32
  u16*   Wth = (u16*)(ws + (size_t)NROW * GCOL + NROW + 8);  // 64*KPAD u16, 16B-aligned
  u16*   Wtl = Wth + (size_t)GCOL * KPAD;

  hipMemsetAsync(xw, 0, (size_t)NROW * GCOL * sizeof(float), stream);
  hipLaunchKernelGGL(prep_w, dim3(CHUNKS), dim3(256), 0, stream, gw, ns, Wth, Wtl);
  hipLaunchKernelGGL(gemm_kernel, dim3(128 * KSPLIT), dim3(256), 0, stream,
                     x, Wth, Wtl, xw);
  hipLaunchKernelGGL(sel_init_kernel, dim3(NROW / 256), dim3(256), 0, stream,
                     xw, gid, gb, sel, res);
  hipLaunchKernelGGL(edge_kernel, dim3(1024), dim3(256), 0, stream,
                     ei, gid, xw, sel, E);
  hipLaunchKernelGGL(hreduce_kernel, dim3(GCOL), dim3(256), 0, stream,
                     w1, sel, b1, fm, fs, w2, res);
  hipLaunchKernelGGL(finalize_kernel, dim3(1), dim3(1), 0, stream,
                     res, b2, out);
}

// Round 3
// 301.570 us; speedup vs baseline: 3.4882x; 1.3871x over previous
//
#include <hip/hip_runtime.h>
#include <hip/hip_bf16.h>

typedef unsigned short u16;
typedef unsigned int   u32;
typedef __attribute__((ext_vector_type(8))) short bf16x8;
typedef __attribute__((ext_vector_type(4))) float f32x4;
typedef __attribute__((ext_vector_type(4))) u32   u32x4;

#define GENES  12132
#define KPAD   12160        // 190 * 64, zero-padded W tail
#define NROW   16384
#define GCOL   64
#define BM     64
#define BK     64
#define CHUNKS 190          // KPAD / BK
#define KTAIL  12096        // (CHUNKS-1)*BK

// ---- fp32 -> bf16 hi/lo split helpers (v_perm packs 2 elts/inst) -----------
__device__ __forceinline__ u32 pack_hi(float x, float y) {
  return __builtin_amdgcn_perm(__float_as_uint(y), __float_as_uint(x), 0x07060302u);
}
__device__ __forceinline__ u32 pack_lo(float x, float y) {
  float lx = x - __uint_as_float(__float_as_uint(x) & 0xFFFF0000u);
  float ly = y - __uint_as_float(__float_as_uint(y) & 0xFFFF0000u);
  return pack_hi(lx, ly);
}
__device__ __forceinline__ void cvt8(const float* __restrict__ p, bf16x8& h8, bf16x8& l8) {
  const f32x4 a = *(const f32x4*)p;
  const f32x4 b = *(const f32x4*)(p + 4);
  u32x4 hv = { pack_hi(a[0], a[1]), pack_hi(a[2], a[3]),
               pack_hi(b[0], b[1]), pack_hi(b[2], b[3]) };
  u32x4 lv = { pack_lo(a[0], a[1]), pack_lo(a[2], a[3]),
               pack_lo(b[0], b[1]), pack_lo(b[2], b[3]) };
  h8 = __builtin_bit_cast(bf16x8, hv);
  l8 = __builtin_bit_cast(bf16x8, lv);
}

__device__ __forceinline__ void gload16(const void* g, void* l) {
  __builtin_amdgcn_global_load_lds(
      (const __attribute__((address_space(1))) void*)g,
      (__attribute__((address_space(3))) void*)l, 16, 0, 0);
}

// ---------------- prep: W'[k][c] = gw[k][c]/ns[k] -> transposed bf16 hi/lo --
// Wth/Wtl layout: [c][k], k padded to KPAD with zeros
__global__ __launch_bounds__(256) void prep_w(
    const float* __restrict__ gw, const float* __restrict__ ns,
    u16* __restrict__ Wth, u16* __restrict__ Wtl) {
  __shared__ u16 th[64 * 72];
  __shared__ u16 tl[64 * 72];
  const int t  = threadIdx.x;
  const int k0 = blockIdx.x * 64;
#pragma unroll
  for (int i = 0; i < 16; ++i) {
    int idx = i * 256 + t;
    int k = idx >> 6, c = idx & 63;
    int gk = k0 + k;
    float wv = 0.f;
    if (gk < GENES) wv = gw[(size_t)gk * GCOL + c] / ns[gk];
    u32 u = __float_as_uint(wv);
    u16 h = (u16)(u >> 16);
    float lf = wv - __uint_as_float(u & 0xFFFF0000u);
    th[c * 72 + k] = h;
    tl[c * 72 + k] = (u16)(__float_as_uint(lf) >> 16);
  }
  __syncthreads();
  const int c  = t >> 2;
  const int kk = (t & 3) * 16;
  uint4 a0 = *(const uint4*)(th + c * 72 + kk);
  uint4 a1 = *(const uint4*)(th + c * 72 + kk + 8);
  uint4 b0 = *(const uint4*)(tl + c * 72 + kk);
  uint4 b1 = *(const uint4*)(tl + c * 72 + kk + 8);
  *(uint4*)(Wth + (size_t)c * KPAD + k0 + kk)     = a0;
  *(uint4*)(Wth + (size_t)c * KPAD + k0 + kk + 8) = a1;
  *(uint4*)(Wtl + (size_t)c * KPAD + k0 + kk)     = b0;
  *(uint4*)(Wtl + (size_t)c * KPAD + k0 + kk + 8) = b1;
}

// ---------------- prep: xpad[N][64] = x[:, KTAIL:GENES] zero-padded ---------
__global__ __launch_bounds__(256) void prep_xpad(
    const float* __restrict__ x, float* __restrict__ xpad) {
  int i = blockIdx.x * 256 + threadIdx.x;   // over NROW*64
  int row = i >> 6, col = i & 63;
  float v = 0.f;
  if (col < GENES - KTAIL) v = x[(size_t)row * GENES + KTAIL + col];
  xpad[i] = v;
}

// ---------------- GEMM: xw[N,64] = x[N,K] @ W'[K,64] (split-bf16 MFMA) ------
// 256 blocks x 512 threads; block owns 64 rows, full K; no atomics.
__global__ __launch_bounds__(512, 2) void gemm_kernel(
    const float* __restrict__ x, const float* __restrict__ xpad,
    const u16* __restrict__ Wth, const u16* __restrict__ Wtl,
    float* __restrict__ xw) {
  __shared__ float Abuf[2][BM * BK];        // 2 x 16 KB, swizzled (32B-pair ^ row&7)
  __shared__ u16   Bbuf[2][2][64 * BK];     // [buf][hi/lo], 8 KB each, (16B ^ c&7)

  const int t    = threadIdx.x;
  const int W    = t >> 6;
  const int lane = t & 63;
  const int r0   = blockIdx.x * BM;

  // --- staging geometry (per-thread, chunk-invariant) ---
  // A: issue j in {0,1}: LDS granule G = j*512 + t; row=G>>4, gcol=G&15
  const int arow0 = t >> 4,        acol0 = t & 15;
  const int arow1 = (512 + t) >> 4, acol1 = (512 + t) & 15;
  const int asrc0 = ((((acol0 >> 1) ^ (arow0 & 7)) << 1) | (acol0 & 1)) << 2; // float ofs in row
  const int asrc1 = ((((acol1 >> 1) ^ (arow1 & 7)) << 1) | (acol1 & 1)) << 2;
  // B: granule G = t; c=G>>3, gcol=G&7; source granule = gcol ^ (c&7)
  const int bc   = t >> 3;
  const int bsrc = ((t & 7) ^ (bc & 7)) << 3;   // u16 ofs in row

  // --- fragment geometry ---
  const int wm = W >> 1, wn = W & 1;
  const int lr = lane & 15;
  const int kg = lane >> 4;
  const int arow = wm * 16 + lr;
  const int aridx0 = arow * 64 + (((0 * 4 + kg) ^ (arow & 7)) << 3);  // float idx
  const int aridx1 = arow * 64 + (((1 * 4 + kg) ^ (arow & 7)) << 3);
  int bidx[2][2];
#pragma unroll
  for (int n2 = 0; n2 < 2; ++n2) {
    int c = (wn * 2 + n2) * 16 + lr;
#pragma unroll
    for (int s = 0; s < 2; ++s)
      bidx[n2][s] = c * 64 + (((s * 4 + kg) ^ (c & 7)) << 3);         // u16 idx
  }

  f32x4 acc[2];
  acc[0] = (f32x4){0.f, 0.f, 0.f, 0.f};
  acc[1] = (f32x4){0.f, 0.f, 0.f, 0.f};

  auto STAGE = [&](int buf, int ch) {
    const float* Ab;
    size_t astr;
    int kof;
    if (ch < CHUNKS - 1) { Ab = x;    astr = GENES; kof = ch * BK; }
    else                 { Ab = xpad; astr = 64;    kof = 0;       }
    const int k0 = ch * BK;
    gload16(Ab + (size_t)(r0 + arow0) * astr + kof + asrc0, &Abuf[buf][(W * 64) * 4]);
    gload16(Ab + (size_t)(r0 + arow1) * astr + kof + asrc1, &Abuf[buf][(512 + W * 64) * 4]);
    gload16(Wth + (size_t)bc * KPAD + k0 + bsrc, &Bbuf[buf][0][(W * 64) * 8]);
    gload16(Wtl + (size_t)bc * KPAD + k0 + bsrc, &Bbuf[buf][1][(W * 64) * 8]);
  };

  STAGE(0, 0);
  STAGE(1, 1);

  for (int ch = 0; ch < CHUNKS; ++ch) {
    const int p = ch & 1;
    if (ch == CHUNKS - 1)
      asm volatile("s_waitcnt vmcnt(0)" ::: "memory");
    else
      asm volatile("s_waitcnt vmcnt(4)" ::: "memory");
    __builtin_amdgcn_s_barrier();

    bf16x8 ah0, al0, ah1, al1;
    cvt8(&Abuf[p][aridx0], ah0, al0);
    cvt8(&Abuf[p][aridx1], ah1, al1);
#pragma unroll
    for (int n2 = 0; n2 < 2; ++n2) {
      bf16x8 bh0 = *(const bf16x8*)&Bbuf[p][0][bidx[n2][0]];
      bf16x8 bl0 = *(const bf16x8*)&Bbuf[p][1][bidx[n2][0]];
      acc[n2] = __builtin_amdgcn_mfma_f32_16x16x32_bf16(ah0, bh0, acc[n2], 0, 0, 0);
      acc[n2] = __builtin_amdgcn_mfma_f32_16x16x32_bf16(al0, bh0, acc[n2], 0, 0, 0);
      acc[n2] = __builtin_amdgcn_mfma_f32_16x16x32_bf16(ah0, bl0, acc[n2], 0, 0, 0);
      bf16x8 bh1 = *(const bf16x8*)&Bbuf[p][0][bidx[n2][1]];
      bf16x8 bl1 = *(const bf16x8*)&Bbuf[p][1][bidx[n2][1]];
      acc[n2] = __builtin_amdgcn_mfma_f32_16x16x32_bf16(ah1, bh1, acc[n2], 0, 0, 0);
      acc[n2] = __builtin_amdgcn_mfma_f32_16x16x32_bf16(al1, bh1, acc[n2], 0, 0, 0);
      acc[n2] = __builtin_amdgcn_mfma_f32_16x16x32_bf16(ah1, bl1, acc[n2], 0, 0, 0);
    }

    asm volatile("s_waitcnt lgkmcnt(0)" ::: "memory");
    __builtin_amdgcn_s_barrier();
    if (ch + 2 < CHUNKS) STAGE(p, ch + 2);
  }

  // epilogue: C/D layout col=lane&15, row=(lane>>4)*4+reg
  const int orow = r0 + wm * 16 + kg * 4;
#pragma unroll
  for (int n2 = 0; n2 < 2; ++n2) {
    const int col = (wn * 2 + n2) * 16 + lr;
#pragma unroll
    for (int j = 0; j < 4; ++j)
      xw[(size_t)(orow + j) * GCOL + col] = acc[n2][j];
  }
}

// ---------------- selected init: sel[i] = xw[i, g_i] + bias[g_i]; res = 0 ---
__global__ __launch_bounds__(256) void sel_init_kernel(
    const float* __restrict__ xw, const int* __restrict__ gid,
    const float* __restrict__ bias, float* __restrict__ sel,
    float* __restrict__ res) {
  int i = blockIdx.x * 256 + threadIdx.x;
  int g = gid[i];
  sel[i] = xw[(size_t)i * GCOL + g] + bias[g];
  if (i == 0) *res = 0.f;
}

// ---------------- edge scatter: sel[dst] += xw[src, g_dst] ------------------
__global__ __launch_bounds__(256) void edge_kernel(
    const int* __restrict__ ei, const int* __restrict__ gid,
    const float* __restrict__ xw, float* __restrict__ sel, int E) {
  int i = blockIdx.x * blockDim.x + threadIdx.x;
  int stride = gridDim.x * blockDim.x;
  for (int e = i; e < E; e += stride) {
    int s = ei[e];
    int d = ei[E + e];
    int g = gid[d];
    atomicAdd(&sel[d], xw[(size_t)s * GCOL + g]);
  }
}

// ---------------- h[k] = w1[k,:] . sel; normalize; res += w2[k]*hn ----------
__global__ __launch_bounds__(256) void hreduce_kernel(
    const float* __restrict__ w1, const float* __restrict__ sel,
    const float* __restrict__ b1, const float* __restrict__ fm,
    const float* __restrict__ fs, const float* __restrict__ w2,
    float* __restrict__ res) {
  int k = blockIdx.x;
  int t = threadIdx.x;
  const float4* wr = reinterpret_cast<const float4*>(w1 + (size_t)k * NROW);
  const float4* sv = reinterpret_cast<const float4*>(sel);
  float sum = 0.f;
  for (int i = t; i < NROW / 4; i += 256) {
    float4 a = wr[i];
    float4 b = sv[i];
    sum += a.x * b.x + a.y * b.y + a.z * b.z + a.w * b.w;
  }
#pragma unroll
  for (int off = 32; off > 0; off >>= 1) sum += __shfl_down(sum, off, 64);
  __shared__ float wsum[4];
  if ((t & 63) == 0) wsum[t >> 6] = sum;
  __syncthreads();
  if (t == 0) {
    float h  = wsum[0] + wsum[1] + wsum[2] + wsum[3] + b1[k];
    float hn = (h - fm[k]) / fs[k];
    atomicAdd(res, w2[k] * hn);
  }
}

// ---------------- finalize: out = sigmoid(res + b2) -------------------------
__global__ void finalize_kernel(const float* __restrict__ res,
                                const float* __restrict__ b2,
                                float* __restrict__ out) {
  float z = *res + b2[0];
  out[0] = 1.f / (1.f + expf(-z));
}

extern "C" void kernel_launch(void* const* d_in, const int* in_sizes, int n_in,
                              void* d_out, int out_size, void* d_ws, size_t ws_size,
                              hipStream_t stream) {
  const float* x    = (const float*)d_in[0];
  const int*   ei   = (const int*)d_in[1];
  const int*   gid  = (const int*)d_in[2];
  const float* ns   = (const float*)d_in[3];
  const float* gw   = (const float*)d_in[4];
  const float* gb   = (const float*)d_in[5];
  const float* w1   = (const float*)d_in[6];
  const float* b1   = (const float*)d_in[7];
  const float* fm   = (const float*)d_in[8];
  const float* fs   = (const float*)d_in[9];
  const float* w2   = (const float*)d_in[10];
  const float* b2   = (const float*)d_in[11];
  float* out = (float*)d_out;

  const int E = in_sizes[1] / 2;

  float* ws   = (float*)d_ws;
  float* xw   = ws;                                  // 1,048,576 f32
  float* sel  = xw + (size_t)NROW * GCOL;            // 16,384 f32
  float* res  = sel + NROW;                          // 1 f32 (+7 pad)
  u16*   Wth  = (u16*)(res + 8);                     // 64*KPAD u16, 16B-aligned
  u16*   Wtl  = Wth + (size_t)GCOL * KPAD;
  float* xpad = (float*)(Wtl + (size_t)GCOL * KPAD); // NROW*64 f32, 16B-aligned

  hipLaunchKernelGGL(prep_w, dim3(CHUNKS), dim3(256), 0, stream, gw, ns, Wth, Wtl);
  hipLaunchKernelGGL(prep_xpad, dim3(NROW * 64 / 256), dim3(256), 0, stream, x, xpad);
  hipLaunchKernelGGL(gemm_kernel, dim3(NROW / BM), dim3(512), 0, stream,
                     x, xpad, Wth, Wtl, xw);
  hipLaunchKernelGGL(sel_init_kernel, dim3(NROW / 256), dim3(256), 0, stream,
                     xw, gid, gb, sel, res);
  hipLaunchKernelGGL(edge_kernel, dim3(1024), dim3(256), 0, stream,
                     ei, gid, xw, sel, E);
  hipLaunchKernelGGL(hreduce_kernel, dim3(GCOL), dim3(256), 0, stream,
                     w1, sel, b1, fm, fs, w2, res);
  hipLaunchKernelGGL(finalize_kernel, dim3(1), dim3(1), 0, stream,
                     res, b2, out);
}